// Round 3
// baseline (1150.089 us; speedup 1.0000x reference)
//
#include <hip/hip_runtime.h>
#include <cmath>

#define NN 1024
#define BB 64
#define WD 64
#define RR 4
#define STRIPES 32   // K2: 32 rows per block (8 waves x 4 rows)

constexpr float EPSF = 1e-6f;

// ---------------- device helpers ----------------
__device__ __forceinline__ float softplusf(float x) {
    return fmaxf(x, 0.f) + log1pf(expf(-fabsf(x)));
}

__device__ __forceinline__ float rfl(float x) {
    return __int_as_float(__builtin_amdgcn_readfirstlane(__float_as_int(x)));
}

// block = 1024 threads (16 waves)
__device__ __forceinline__ float block_sum(float v, float* red, float* bc) {
#pragma unroll
    for (int o = 1; o < 64; o <<= 1) v += __shfl_xor(v, o, 64);
    const int wid = threadIdx.x >> 6, lane = threadIdx.x & 63;
    if (lane == 0) red[wid] = v;
    __syncthreads();
    if (wid == 0) {
        float x = (lane < 16) ? red[lane] : 0.f;
#pragma unroll
        for (int o = 1; o < 16; o <<= 1) x += __shfl_xor(x, o, 64);
        if (lane == 0) bc[0] = x;
    }
    __syncthreads();
    return bc[0];
}

__device__ __forceinline__ float block_max(float v, float* red, float* bc) {
#pragma unroll
    for (int o = 1; o < 64; o <<= 1) v = fmaxf(v, __shfl_xor(v, o, 64));
    const int wid = threadIdx.x >> 6, lane = threadIdx.x & 63;
    if (lane == 0) red[wid] = v;
    __syncthreads();
    if (wid == 0) {
        float x = (lane < 16) ? red[lane] : -INFINITY;
#pragma unroll
        for (int o = 1; o < 16; o <<= 1) x = fmaxf(x, __shfl_xor(x, o, 64));
        if (lane == 0) bc[0] = x;
    }
    __syncthreads();
    return bc[0];
}

__device__ __forceinline__ float4 block_sum4(float4 v, float4* red, float4* bc) {
#pragma unroll
    for (int o = 1; o < 64; o <<= 1) {
        v.x += __shfl_xor(v.x, o, 64); v.y += __shfl_xor(v.y, o, 64);
        v.z += __shfl_xor(v.z, o, 64); v.w += __shfl_xor(v.w, o, 64);
    }
    const int wid = threadIdx.x >> 6, lane = threadIdx.x & 63;
    if (lane == 0) red[wid] = v;
    __syncthreads();
    if (wid == 0) {
        float4 x;
        if (lane < 16) x = red[lane];
        else { x.x = 0.f; x.y = 0.f; x.z = 0.f; x.w = 0.f; }
#pragma unroll
        for (int o = 1; o < 16; o <<= 1) {
            x.x += __shfl_xor(x.x, o, 64); x.y += __shfl_xor(x.y, o, 64);
            x.z += __shfl_xor(x.z, o, 64); x.w += __shfl_xor(x.w, o, 64);
        }
        if (lane == 0) bc[0] = x;
    }
    __syncthreads();
    return bc[0];
}

__device__ __forceinline__ float4 block_max4(float4 v, float4* red, float4* bc) {
#pragma unroll
    for (int o = 1; o < 64; o <<= 1) {
        v.x = fmaxf(v.x, __shfl_xor(v.x, o, 64)); v.y = fmaxf(v.y, __shfl_xor(v.y, o, 64));
        v.z = fmaxf(v.z, __shfl_xor(v.z, o, 64)); v.w = fmaxf(v.w, __shfl_xor(v.w, o, 64));
    }
    const int wid = threadIdx.x >> 6, lane = threadIdx.x & 63;
    if (lane == 0) red[wid] = v;
    __syncthreads();
    if (wid == 0) {
        float4 x;
        if (lane < 16) x = red[lane];
        else { x.x = -INFINITY; x.y = -INFINITY; x.z = -INFINITY; x.w = -INFINITY; }
#pragma unroll
        for (int o = 1; o < 16; o <<= 1) {
            x.x = fmaxf(x.x, __shfl_xor(x.x, o, 64)); x.y = fmaxf(x.y, __shfl_xor(x.y, o, 64));
            x.z = fmaxf(x.z, __shfl_xor(x.z, o, 64)); x.w = fmaxf(x.w, __shfl_xor(x.w, o, 64));
        }
        if (lane == 0) bc[0] = x;
    }
    __syncthreads();
    return bc[0];
}

// ---------------- K1: per-batch prep (also zero-inits colU) ----------------
__global__ __launch_bounds__(1024) void prep_kernel(
    const float* __restrict__ memory, const float* __restrict__ prw,
    const float* __restrict__ pww, const float* __restrict__ pusage,
    const float* __restrict__ pprec,
    const float* __restrict__ rkeys_g, const float* __restrict__ rstr_g,
    const float* __restrict__ wkeys_g, const float* __restrict__ wstr_g,
    const float* __restrict__ wvec_g, const float* __restrict__ evec_g,
    const float* __restrict__ fg_g, const float* __restrict__ ag_g,
    const float* __restrict__ wg_g,
    float* __restrict__ wwG, float* __restrict__ rcG,
    float* __restrict__ SrpG, float* __restrict__ SuwwG,
    float* __restrict__ colU)
{
    __shared__ float wkey[WD], wvecS[WD], evecS[WD], rkey[RR * WD];
    __shared__ float skey[NN];
    __shared__ int   sidx[NN];
    __shared__ float pArr[NN], wcArr[NN], allocArr[NN];
    __shared__ float red1[16], bc1[1];
    __shared__ float4 red4[16], bc4[1];

    const int b = blockIdx.x, tid = threadIdx.x, n = tid;

    // zero-init colU[b][8][1024] for K2's atomic accumulation
#pragma unroll
    for (int k = 0; k < 8; ++k)
        colU[((size_t)b << 13) + (k << 10) + tid] = 0.f;

    if (tid < WD) {
        wkey[tid]  = wkeys_g[b * WD + tid];
        wvecS[tid] = wvec_g[b * WD + tid];
        evecS[tid] = evec_g[b * WD + tid];
    } else if (tid >= 128 && tid < 128 + RR * WD) {
        int k = tid - 128;
        rkey[k] = rkeys_g[b * RR * WD + k];
    }
    __syncthreads();

    // ---- usage after free gates ----
    float ur[RR];
#pragma unroll
    for (int r = 0; r < RR; ++r) ur[r] = prw[((size_t)b * RR + r) * NN + n];
    const float pw = pww[b * NN + n];
    const float pu = pusage[b * NN + n];
    float usage = pu + (1.f - pu) * pw;
    float phi = 1.f;
#pragma unroll
    for (int r = 0; r < RR; ++r) phi *= (1.f - fg_g[b * RR + r] * ur[r]);
    usage *= phi;

    // ---- write content weights (cosine + softmax) ----
    const float* mrow = memory + ((size_t)b * NN + n) * WD;
    float dot = 0.f, nrm = 0.f, knrm = 0.f;
#pragma unroll 4
    for (int w4 = 0; w4 < WD / 4; ++w4) {
        const float4 m = *(const float4*)(mrow + w4 * 4);
        const float4 k = *(const float4*)(wkey + w4 * 4);
        dot  += m.x * k.x + m.y * k.y + m.z * k.z + m.w * k.w;
        nrm  += m.x * m.x + m.y * m.y + m.z * m.z + m.w * m.w;
        knrm += k.x * k.x + k.y * k.y + k.z * k.z + k.w * k.w;
    }
    const float sim = dot / (sqrtf(knrm + EPSF) * sqrtf(nrm + EPSF) + EPSF);
    const float sharp = sim * softplusf(wstr_g[b]);
    const float mxw = block_max(sharp, red1, bc1);
    const float exw = expf(sharp - mxw);
    const float smw = block_sum(exw, red1, bc1);
    wcArr[n] = exw / smw;

    // ---- allocation: stable descending sort of nonusage ----
    const float ue = EPSF + (1.f - EPSF) * usage;
    skey[n] = 1.f - ue;
    sidx[n] = n;
    __syncthreads();
    for (int k = 2; k <= NN; k <<= 1) {
        for (int j = k >> 1; j > 0; j >>= 1) {
            const int ixj = tid ^ j;
            if (ixj > tid) {
                const float ka = skey[tid], kb = skey[ixj];
                const int ia = sidx[tid], ib = sidx[ixj];
                const bool precBA = (kb > ka) || (kb == ka && ib < ia);
                const bool precAB = (ka > kb) || (ka == kb && ia < ib);
                const bool dosw = ((tid & k) == 0) ? precBA : precAB;
                if (dosw) { skey[tid] = kb; skey[ixj] = ka; sidx[tid] = ib; sidx[ixj] = ia; }
            }
            __syncthreads();
        }
    }
    // exclusive product scan of sorted usage
    pArr[n] = (n == 0) ? 1.f : (1.f - skey[n - 1]);
    __syncthreads();
    for (int off = 1; off < NN; off <<= 1) {
        const float t = (n >= off) ? pArr[n - off] : 1.f;
        __syncthreads();
        pArr[n] *= t;
        __syncthreads();
    }
    allocArr[sidx[n]] = skey[n] * pArr[n];
    __syncthreads();

    const float agv = ag_g[b], wgv = wg_g[b];
    const float ww = wgv * (agv * allocArr[n] + (1.f - agv) * wcArr[n]);
    wwG[b * NN + n] = ww;

    // ---- read content weights vs memory_new (recomputed inline) ----
    float rdot0 = 0, rdot1 = 0, rdot2 = 0, rdot3 = 0, nn2 = 0;
    float rk0 = 0, rk1 = 0, rk2 = 0, rk3 = 0;
#pragma unroll 4
    for (int w4 = 0; w4 < WD / 4; ++w4) {
        const float4 m = *(const float4*)(mrow + w4 * 4);
        const float4 e = *(const float4*)(evecS + w4 * 4);
        const float4 v = *(const float4*)(wvecS + w4 * 4);
        float4 mn_;
        mn_.x = m.x * (1.f - ww * e.x) + ww * v.x;
        mn_.y = m.y * (1.f - ww * e.y) + ww * v.y;
        mn_.z = m.z * (1.f - ww * e.z) + ww * v.z;
        mn_.w = m.w * (1.f - ww * e.w) + ww * v.w;
        nn2 += mn_.x * mn_.x + mn_.y * mn_.y + mn_.z * mn_.z + mn_.w * mn_.w;
        const float4 k0 = *(const float4*)(rkey + 0 * WD + w4 * 4);
        const float4 k1 = *(const float4*)(rkey + 1 * WD + w4 * 4);
        const float4 k2 = *(const float4*)(rkey + 2 * WD + w4 * 4);
        const float4 k3 = *(const float4*)(rkey + 3 * WD + w4 * 4);
        rdot0 += k0.x * mn_.x + k0.y * mn_.y + k0.z * mn_.z + k0.w * mn_.w;
        rdot1 += k1.x * mn_.x + k1.y * mn_.y + k1.z * mn_.z + k1.w * mn_.w;
        rdot2 += k2.x * mn_.x + k2.y * mn_.y + k2.z * mn_.z + k2.w * mn_.w;
        rdot3 += k3.x * mn_.x + k3.y * mn_.y + k3.z * mn_.z + k3.w * mn_.w;
        rk0 += k0.x * k0.x + k0.y * k0.y + k0.z * k0.z + k0.w * k0.w;
        rk1 += k1.x * k1.x + k1.y * k1.y + k1.z * k1.z + k1.w * k1.w;
        rk2 += k2.x * k2.x + k2.y * k2.y + k2.z * k2.z + k2.w * k2.w;
        rk3 += k3.x * k3.x + k3.y * k3.y + k3.z * k3.z + k3.w * k3.w;
    }
    const float mnn = sqrtf(nn2 + EPSF);
    float4 sharp4;
    sharp4.x = rdot0 / (sqrtf(rk0 + EPSF) * mnn + EPSF) * softplusf(rstr_g[b * RR + 0]);
    sharp4.y = rdot1 / (sqrtf(rk1 + EPSF) * mnn + EPSF) * softplusf(rstr_g[b * RR + 1]);
    sharp4.z = rdot2 / (sqrtf(rk2 + EPSF) * mnn + EPSF) * softplusf(rstr_g[b * RR + 2]);
    sharp4.w = rdot3 / (sqrtf(rk3 + EPSF) * mnn + EPSF) * softplusf(rstr_g[b * RR + 3]);
    const float4 mx4 = block_max4(sharp4, red4, bc4);
    float4 e4;
    e4.x = expf(sharp4.x - mx4.x); e4.y = expf(sharp4.y - mx4.y);
    e4.z = expf(sharp4.z - mx4.z); e4.w = expf(sharp4.w - mx4.w);
    const float4 s4 = block_sum4(e4, red4, bc4);
    rcG[((size_t)b * RR + 0) * NN + n] = e4.x / s4.x;
    rcG[((size_t)b * RR + 1) * NN + n] = e4.y / s4.y;
    rcG[((size_t)b * RR + 2) * NN + n] = e4.z / s4.z;
    rcG[((size_t)b * RR + 3) * NN + n] = e4.w / s4.w;

    // ---- scalar sums S_rp, S_uww ----
    const float prec_n = pprec[b * NN + n];
    float4 sp4, sw4;
    sp4.x = ur[0] * prec_n; sp4.y = ur[1] * prec_n; sp4.z = ur[2] * prec_n; sp4.w = ur[3] * prec_n;
    const float4 SrpV = block_sum4(sp4, red4, bc4);
    sw4.x = ur[0] * ww; sw4.y = ur[1] * ww; sw4.z = ur[2] * ww; sw4.w = ur[3] * ww;
    const float4 SuwwV = block_sum4(sw4, red4, bc4);
    if (tid == 0) {
        SrpG[b * RR + 0] = SrpV.x; SrpG[b * RR + 1] = SrpV.y;
        SrpG[b * RR + 2] = SrpV.z; SrpG[b * RR + 3] = SrpV.w;
        SuwwG[b * RR + 0] = SuwwV.x; SuwwG[b * RR + 1] = SuwwV.y;
        SuwwG[b * RR + 2] = SuwwV.z; SuwwG[b * RR + 3] = SuwwV.w;
    }
}

// ---------------- K2: single fused pass over prev_link (256 MB) ----------------
// grid (32 stripes, 64 b), 512 thr = 8 waves x 4 rows each.
// Row sums: per-lane reg accumulators (racc[4][8] = 32 VGPR), butterfly-reduced
//           once per block, non-atomic store (rows are block-exclusive).
// Col sums: wave-uniform u scalars (SGPR via readfirstlane), per-chunk ds_add
//           into 32KB LDS colAcc, block-end global-atomic flush into colU (2MB).
// uw = u*ww computed on the fly (valw = val*ww) -- no uwG buffer.
__global__ __launch_bounds__(512, 6) void link_kernel(
    const float* __restrict__ L, const float* __restrict__ prw,
    const float* __restrict__ wwG,
    float* __restrict__ rowP,    // [b][8][1024]
    float* __restrict__ colU,    // [b][8][1024], atomic-accumulated
    float* __restrict__ diagG)   // [b][1024]
{
    __shared__ float colAcc[8 * NN];   // 32 KB

    const int s = blockIdx.x, b = blockIdx.y;
    const int t = threadIdx.x, lane = t & 63, wid = t >> 6;   // wid 0..7

    // zero colAcc
#pragma unroll
    for (int k = 0; k < 16; ++k) colAcc[t + k * 512] = 0.f;
    __syncthreads();

    const int n0 = s * 32;
    const int nb = n0 + wid * 4;        // this wave's first row

    const float* ub = prw + ((size_t)(b * RR) << 10);   // u[r][col] = ub[(r<<10)+col]
    const float* wb = wwG + ((size_t)b << 10);
    const float* Lb = L + ((size_t)b << 20);

    // wave-uniform scalars for this wave's 4 rows (SGPRs)
    float us_u[4][4], us_uw[4][4];
#pragma unroll
    for (int rr = 0; rr < 4; ++rr) {
        const float wwr = rfl(wb[nb + rr]);
#pragma unroll
        for (int r = 0; r < 4; ++r) {
            const float u = rfl(ub[(r << 10) + nb + rr]);
            us_u[rr][r]  = u;
            us_uw[rr][r] = rfl(u * wwr);
        }
    }

    float racc[4][8];
#pragma unroll
    for (int rr = 0; rr < 4; ++rr)
#pragma unroll
        for (int v = 0; v < 8; ++v) racc[rr][v] = 0.f;

#pragma unroll 1
    for (int cc = 0; cc < 16; ++cc) {
        const int c = (cc + (wid << 1)) & 15;   // stagger chunks across waves
        const int col = (c << 6) + lane;

        const float u0 = ub[col];
        const float u1 = ub[1024 + col];
        const float u2 = ub[2048 + col];
        const float u3 = ub[3072 + col];
        const float wc = wb[col];

        float cacc[8] = {0.f, 0.f, 0.f, 0.f, 0.f, 0.f, 0.f, 0.f};
#pragma unroll
        for (int rr = 0; rr < 4; ++rr) {
            const float val  = Lb[((size_t)(nb + rr) << 10) + col];
            const float valw = val * wc;
            racc[rr][0] = fmaf(val,  u0, racc[rr][0]);
            racc[rr][1] = fmaf(val,  u1, racc[rr][1]);
            racc[rr][2] = fmaf(val,  u2, racc[rr][2]);
            racc[rr][3] = fmaf(val,  u3, racc[rr][3]);
            racc[rr][4] = fmaf(valw, u0, racc[rr][4]);
            racc[rr][5] = fmaf(valw, u1, racc[rr][5]);
            racc[rr][6] = fmaf(valw, u2, racc[rr][6]);
            racc[rr][7] = fmaf(valw, u3, racc[rr][7]);
            cacc[0] = fmaf(val, us_u[rr][0],  cacc[0]);
            cacc[1] = fmaf(val, us_u[rr][1],  cacc[1]);
            cacc[2] = fmaf(val, us_u[rr][2],  cacc[2]);
            cacc[3] = fmaf(val, us_u[rr][3],  cacc[3]);
            cacc[4] = fmaf(val, us_uw[rr][0], cacc[4]);
            cacc[5] = fmaf(val, us_uw[rr][1], cacc[5]);
            cacc[6] = fmaf(val, us_uw[rr][2], cacc[6]);
            cacc[7] = fmaf(val, us_uw[rr][3], cacc[7]);
        }
#pragma unroll
        for (int v = 0; v < 8; ++v)
            unsafeAtomicAdd(&colAcc[(v << 10) + col], cacc[v]);
    }

    // diagonal extraction: wave's 4 rows (lines are L1/L2 hot)
    if (lane < 4) {
        const int n = nb + lane;
        diagG[(b << 10) + n] = Lb[((size_t)n << 10) + n];
    }

    // butterfly-reduce racc over lanes; value q = rr*8+v stored by lane q
#pragma unroll
    for (int rr = 0; rr < 4; ++rr)
#pragma unroll
        for (int v = 0; v < 8; ++v) {
            float x = racc[rr][v];
            x += __shfl_xor(x, 1, 64);  x += __shfl_xor(x, 2, 64);
            x += __shfl_xor(x, 4, 64);  x += __shfl_xor(x, 8, 64);
            x += __shfl_xor(x, 16, 64); x += __shfl_xor(x, 32, 64);
            if (lane == rr * 8 + v)
                rowP[(((size_t)b * 8 + v) << 10) + nb + rr] = x;
        }

    __syncthreads();
    // flush colAcc -> global colU with device-scope fp32 atomics
#pragma unroll
    for (int k = 0; k < 16; ++k) {
        const int idx = t + k * 512;
        unsafeAtomicAdd(&colU[((size_t)b << 13) + idx], colAcc[idx]);
    }
}

// ---------------- K3: assemble read weights + read_words ----------------
__global__ __launch_bounds__(256) void combine_kernel(
    const float* __restrict__ memory, const float* __restrict__ prw,
    const float* __restrict__ pprec, const float* __restrict__ diagG,
    const float* __restrict__ evec_g, const float* __restrict__ wvec_g,
    const float* __restrict__ rmode_g,
    const float* __restrict__ wwG, const float* __restrict__ rcG,
    const float* __restrict__ rowP, const float* __restrict__ colU,
    const float* __restrict__ SrpG, const float* __restrict__ SuwwG,
    float* __restrict__ out)
{
    __shared__ float rwL[RR][256];
    __shared__ float wwS[256];

    const int b = blockIdx.y;
    const int n0 = blockIdx.x * 256;
    const int t = threadIdx.x;
    const int n = n0 + t;

    const float wwn = wwG[b * NN + n];
    wwS[t] = wwn;
    const float prec_n = pprec[b * NN + n];
    const float diag = diagG[(b << 10) + n];

#pragma unroll
    for (int r = 0; r < RR; ++r) {
        const size_t idx = ((size_t)b * RR + r) * NN + n;
        const float un = prw[idx];
        const float rc = rcG[idx];
        const float ru = rowP[(((size_t)b * 8 + r) << 10) + n];
        const float rv = rowP[(((size_t)b * 8 + 4 + r) << 10) + n];
        const float cuv = colU[((size_t)b << 13) + (r << 10) + n];
        const float cvv = colU[((size_t)b << 13) + ((4 + r) << 10) + n];
        const float Srp = SrpG[b * RR + r], Suww = SuwwG[b * RR + r];
        const float corr = un * (1.f - 2.f * wwn) * diag;
        const float fwd = (1.f - wwn) * ru - rv - corr + wwn * (Srp - un * prec_n);
        const float bwd = (1.f - wwn) * cuv - cvv - corr + prec_n * (Suww - un * wwn);
        const float m0 = rmode_g[((size_t)b * RR + r) * 3 + 0];
        const float m1 = rmode_g[((size_t)b * RR + r) * 3 + 1];
        const float m2 = rmode_g[((size_t)b * RR + r) * 3 + 2];
        const float mx = fmaxf(m0, fmaxf(m1, m2));
        const float e0 = expf(m0 - mx), e1 = expf(m1 - mx), e2 = expf(m2 - mx);
        const float inv = 1.f / (e0 + e1 + e2);
        rwL[r][t] = (e2 * inv) * rc + (e1 * inv) * fwd + (e0 * inv) * bwd;
    }
    __syncthreads();

    // partial read_words over this n-chunk
    const int r = t >> 6, w = t & 63;
    const float ev = evec_g[b * WD + w], wv = wvec_g[b * WD + w];
    float acc = 0.f;
    const float* mb = memory + ((size_t)b * NN + n0) * WD;
#pragma unroll 8
    for (int i = 0; i < 256; ++i) {
        const float m = mb[(size_t)i * WD + w];
        const float wwi = wwS[i];
        const float mn_ = m * (1.f - wwi * ev) + wwi * wv;
        acc = fmaf(rwL[r][i], mn_, acc);
    }
    unsafeAtomicAdd(&out[((size_t)b * RR + r) * WD + w], acc);
}

// ---------------- launch ----------------
extern "C" void kernel_launch(void* const* d_in, const int* in_sizes, int n_in,
                              void* d_out, int out_size, void* d_ws, size_t ws_size,
                              hipStream_t stream) {
    const float* memory = (const float*)d_in[0];
    const float* prw    = (const float*)d_in[1];
    const float* pww    = (const float*)d_in[2];
    const float* pusage = (const float*)d_in[3];
    const float* plink  = (const float*)d_in[4];
    const float* pprec  = (const float*)d_in[5];
    const float* rkeys  = (const float*)d_in[6];
    const float* rstr   = (const float*)d_in[7];
    const float* wkeys  = (const float*)d_in[8];
    const float* wstr   = (const float*)d_in[9];
    const float* wvec   = (const float*)d_in[10];
    const float* evec   = (const float*)d_in[11];
    const float* fg     = (const float*)d_in[12];
    const float* ag     = (const float*)d_in[13];
    const float* wg     = (const float*)d_in[14];
    const float* rmode  = (const float*)d_in[15];

    float* ws = (float*)d_ws;
    const size_t BN   = (size_t)BB * NN;        // 65536
    const size_t BRN  = (size_t)BB * RR * NN;   // 262144
    const size_t B8N  = (size_t)BB * 8 * NN;    // 524288

    float* wwG   = ws;
    float* rcG   = wwG + BN;
    float* rowP  = rcG + BRN;
    float* colU  = rowP + B8N;
    float* diagG = colU + B8N;
    float* Srp   = diagG + BN;
    float* Suww  = Srp + (size_t)BB * RR;

    hipMemsetAsync(d_out, 0, (size_t)out_size * sizeof(float), stream);

    prep_kernel<<<BB, 1024, 0, stream>>>(memory, prw, pww, pusage, pprec,
                                         rkeys, rstr, wkeys, wstr, wvec, evec,
                                         fg, ag, wg, wwG, rcG, Srp, Suww, colU);
    link_kernel<<<dim3(STRIPES, BB), 512, 0, stream>>>(plink, prw, wwG,
                                                       rowP, colU, diagG);
    combine_kernel<<<dim3(4, BB), 256, 0, stream>>>(memory, prw, pprec, diagG,
                                                    evec, wvec, rmode,
                                                    wwG, rcG, rowP, colU,
                                                    Srp, Suww, (float*)d_out);
}

// Round 4
// 632.497 us; speedup vs baseline: 1.8183x; 1.8183x over previous
//
#include <hip/hip_runtime.h>
#include <cmath>

#define NN 1024
#define BB 64
#define WD 64
#define RR 4

constexpr float EPSF = 1e-6f;

// ---------------- device helpers ----------------
__device__ __forceinline__ float softplusf(float x) {
    return fmaxf(x, 0.f) + log1pf(expf(-fabsf(x)));
}

// block = 1024 threads (16 waves)
__device__ __forceinline__ float block_sum(float v, float* red, float* bc) {
#pragma unroll
    for (int o = 1; o < 64; o <<= 1) v += __shfl_xor(v, o, 64);
    const int wid = threadIdx.x >> 6, lane = threadIdx.x & 63;
    if (lane == 0) red[wid] = v;
    __syncthreads();
    if (wid == 0) {
        float x = (lane < 16) ? red[lane] : 0.f;
#pragma unroll
        for (int o = 1; o < 16; o <<= 1) x += __shfl_xor(x, o, 64);
        if (lane == 0) bc[0] = x;
    }
    __syncthreads();
    return bc[0];
}

__device__ __forceinline__ float block_max(float v, float* red, float* bc) {
#pragma unroll
    for (int o = 1; o < 64; o <<= 1) v = fmaxf(v, __shfl_xor(v, o, 64));
    const int wid = threadIdx.x >> 6, lane = threadIdx.x & 63;
    if (lane == 0) red[wid] = v;
    __syncthreads();
    if (wid == 0) {
        float x = (lane < 16) ? red[lane] : -INFINITY;
#pragma unroll
        for (int o = 1; o < 16; o <<= 1) x = fmaxf(x, __shfl_xor(x, o, 64));
        if (lane == 0) bc[0] = x;
    }
    __syncthreads();
    return bc[0];
}

__device__ __forceinline__ float4 block_sum4(float4 v, float4* red, float4* bc) {
#pragma unroll
    for (int o = 1; o < 64; o <<= 1) {
        v.x += __shfl_xor(v.x, o, 64); v.y += __shfl_xor(v.y, o, 64);
        v.z += __shfl_xor(v.z, o, 64); v.w += __shfl_xor(v.w, o, 64);
    }
    const int wid = threadIdx.x >> 6, lane = threadIdx.x & 63;
    if (lane == 0) red[wid] = v;
    __syncthreads();
    if (wid == 0) {
        float4 x;
        if (lane < 16) x = red[lane];
        else { x.x = 0.f; x.y = 0.f; x.z = 0.f; x.w = 0.f; }
#pragma unroll
        for (int o = 1; o < 16; o <<= 1) {
            x.x += __shfl_xor(x.x, o, 64); x.y += __shfl_xor(x.y, o, 64);
            x.z += __shfl_xor(x.z, o, 64); x.w += __shfl_xor(x.w, o, 64);
        }
        if (lane == 0) bc[0] = x;
    }
    __syncthreads();
    return bc[0];
}

__device__ __forceinline__ float4 block_max4(float4 v, float4* red, float4* bc) {
#pragma unroll
    for (int o = 1; o < 64; o <<= 1) {
        v.x = fmaxf(v.x, __shfl_xor(v.x, o, 64)); v.y = fmaxf(v.y, __shfl_xor(v.y, o, 64));
        v.z = fmaxf(v.z, __shfl_xor(v.z, o, 64)); v.w = fmaxf(v.w, __shfl_xor(v.w, o, 64));
    }
    const int wid = threadIdx.x >> 6, lane = threadIdx.x & 63;
    if (lane == 0) red[wid] = v;
    __syncthreads();
    if (wid == 0) {
        float4 x;
        if (lane < 16) x = red[lane];
        else { x.x = -INFINITY; x.y = -INFINITY; x.z = -INFINITY; x.w = -INFINITY; }
#pragma unroll
        for (int o = 1; o < 16; o <<= 1) {
            x.x = fmaxf(x.x, __shfl_xor(x.x, o, 64)); x.y = fmaxf(x.y, __shfl_xor(x.y, o, 64));
            x.z = fmaxf(x.z, __shfl_xor(x.z, o, 64)); x.w = fmaxf(x.w, __shfl_xor(x.w, o, 64));
        }
        if (lane == 0) bc[0] = x;
    }
    __syncthreads();
    return bc[0];
}

// ---------------- K1: per-batch prep (also zero-inits colU) ----------------
__global__ __launch_bounds__(1024) void prep_kernel(
    const float* __restrict__ memory, const float* __restrict__ prw,
    const float* __restrict__ pww, const float* __restrict__ pusage,
    const float* __restrict__ pprec,
    const float* __restrict__ rkeys_g, const float* __restrict__ rstr_g,
    const float* __restrict__ wkeys_g, const float* __restrict__ wstr_g,
    const float* __restrict__ wvec_g, const float* __restrict__ evec_g,
    const float* __restrict__ fg_g, const float* __restrict__ ag_g,
    const float* __restrict__ wg_g,
    float* __restrict__ wwG, float* __restrict__ rcG,
    float* __restrict__ SrpG, float* __restrict__ SuwwG,
    float* __restrict__ colU)
{
    __shared__ float wkey[WD], wvecS[WD], evecS[WD], rkey[RR * WD];
    __shared__ float skey[NN];
    __shared__ int   sidx[NN];
    __shared__ float pArr[NN], wcArr[NN], allocArr[NN];
    __shared__ float red1[16], bc1[1];
    __shared__ float4 red4[16], bc4[1];

    const int b = blockIdx.x, tid = threadIdx.x, n = tid;

    // zero-init colU[b][8][1024] for col_kernel's atomic accumulation
#pragma unroll
    for (int k = 0; k < 8; ++k)
        colU[((size_t)b << 13) + (k << 10) + tid] = 0.f;

    if (tid < WD) {
        wkey[tid]  = wkeys_g[b * WD + tid];
        wvecS[tid] = wvec_g[b * WD + tid];
        evecS[tid] = evec_g[b * WD + tid];
    } else if (tid >= 128 && tid < 128 + RR * WD) {
        int k = tid - 128;
        rkey[k] = rkeys_g[b * RR * WD + k];
    }
    __syncthreads();

    // ---- usage after free gates ----
    float ur[RR];
#pragma unroll
    for (int r = 0; r < RR; ++r) ur[r] = prw[((size_t)b * RR + r) * NN + n];
    const float pw = pww[b * NN + n];
    const float pu = pusage[b * NN + n];
    float usage = pu + (1.f - pu) * pw;
    float phi = 1.f;
#pragma unroll
    for (int r = 0; r < RR; ++r) phi *= (1.f - fg_g[b * RR + r] * ur[r]);
    usage *= phi;

    // ---- write content weights (cosine + softmax) ----
    const float* mrow = memory + ((size_t)b * NN + n) * WD;
    float dot = 0.f, nrm = 0.f, knrm = 0.f;
#pragma unroll 4
    for (int w4 = 0; w4 < WD / 4; ++w4) {
        const float4 m = *(const float4*)(mrow + w4 * 4);
        const float4 k = *(const float4*)(wkey + w4 * 4);
        dot  += m.x * k.x + m.y * k.y + m.z * k.z + m.w * k.w;
        nrm  += m.x * m.x + m.y * m.y + m.z * m.z + m.w * m.w;
        knrm += k.x * k.x + k.y * k.y + k.z * k.z + k.w * k.w;
    }
    const float sim = dot / (sqrtf(knrm + EPSF) * sqrtf(nrm + EPSF) + EPSF);
    const float sharp = sim * softplusf(wstr_g[b]);
    const float mxw = block_max(sharp, red1, bc1);
    const float exw = expf(sharp - mxw);
    const float smw = block_sum(exw, red1, bc1);
    wcArr[n] = exw / smw;

    // ---- allocation: stable descending sort of nonusage ----
    const float ue = EPSF + (1.f - EPSF) * usage;
    skey[n] = 1.f - ue;
    sidx[n] = n;
    __syncthreads();
    for (int k = 2; k <= NN; k <<= 1) {
        for (int j = k >> 1; j > 0; j >>= 1) {
            const int ixj = tid ^ j;
            if (ixj > tid) {
                const float ka = skey[tid], kb = skey[ixj];
                const int ia = sidx[tid], ib = sidx[ixj];
                const bool precBA = (kb > ka) || (kb == ka && ib < ia);
                const bool precAB = (ka > kb) || (ka == kb && ia < ib);
                const bool dosw = ((tid & k) == 0) ? precBA : precAB;
                if (dosw) { skey[tid] = kb; skey[ixj] = ka; sidx[tid] = ib; sidx[ixj] = ia; }
            }
            __syncthreads();
        }
    }
    // exclusive product scan of sorted usage
    pArr[n] = (n == 0) ? 1.f : (1.f - skey[n - 1]);
    __syncthreads();
    for (int off = 1; off < NN; off <<= 1) {
        const float t = (n >= off) ? pArr[n - off] : 1.f;
        __syncthreads();
        pArr[n] *= t;
        __syncthreads();
    }
    allocArr[sidx[n]] = skey[n] * pArr[n];
    __syncthreads();

    const float agv = ag_g[b], wgv = wg_g[b];
    const float ww = wgv * (agv * allocArr[n] + (1.f - agv) * wcArr[n]);
    wwG[b * NN + n] = ww;

    // ---- read content weights vs memory_new (recomputed inline) ----
    float rdot0 = 0, rdot1 = 0, rdot2 = 0, rdot3 = 0, nn2 = 0;
    float rk0 = 0, rk1 = 0, rk2 = 0, rk3 = 0;
#pragma unroll 4
    for (int w4 = 0; w4 < WD / 4; ++w4) {
        const float4 m = *(const float4*)(mrow + w4 * 4);
        const float4 e = *(const float4*)(evecS + w4 * 4);
        const float4 v = *(const float4*)(wvecS + w4 * 4);
        float4 mn_;
        mn_.x = m.x * (1.f - ww * e.x) + ww * v.x;
        mn_.y = m.y * (1.f - ww * e.y) + ww * v.y;
        mn_.z = m.z * (1.f - ww * e.z) + ww * v.z;
        mn_.w = m.w * (1.f - ww * e.w) + ww * v.w;
        nn2 += mn_.x * mn_.x + mn_.y * mn_.y + mn_.z * mn_.z + mn_.w * mn_.w;
        const float4 k0 = *(const float4*)(rkey + 0 * WD + w4 * 4);
        const float4 k1 = *(const float4*)(rkey + 1 * WD + w4 * 4);
        const float4 k2 = *(const float4*)(rkey + 2 * WD + w4 * 4);
        const float4 k3 = *(const float4*)(rkey + 3 * WD + w4 * 4);
        rdot0 += k0.x * mn_.x + k0.y * mn_.y + k0.z * mn_.z + k0.w * mn_.w;
        rdot1 += k1.x * mn_.x + k1.y * mn_.y + k1.z * mn_.z + k1.w * mn_.w;
        rdot2 += k2.x * mn_.x + k2.y * mn_.y + k2.z * mn_.z + k2.w * mn_.w;
        rdot3 += k3.x * mn_.x + k3.y * mn_.y + k3.z * mn_.z + k3.w * mn_.w;
        rk0 += k0.x * k0.x + k0.y * k0.y + k0.z * k0.z + k0.w * k0.w;
        rk1 += k1.x * k1.x + k1.y * k1.y + k1.z * k1.z + k1.w * k1.w;
        rk2 += k2.x * k2.x + k2.y * k2.y + k2.z * k2.z + k2.w * k2.w;
        rk3 += k3.x * k3.x + k3.y * k3.y + k3.z * k3.z + k3.w * k3.w;
    }
    const float mnn = sqrtf(nn2 + EPSF);
    float4 sharp4;
    sharp4.x = rdot0 / (sqrtf(rk0 + EPSF) * mnn + EPSF) * softplusf(rstr_g[b * RR + 0]);
    sharp4.y = rdot1 / (sqrtf(rk1 + EPSF) * mnn + EPSF) * softplusf(rstr_g[b * RR + 1]);
    sharp4.z = rdot2 / (sqrtf(rk2 + EPSF) * mnn + EPSF) * softplusf(rstr_g[b * RR + 2]);
    sharp4.w = rdot3 / (sqrtf(rk3 + EPSF) * mnn + EPSF) * softplusf(rstr_g[b * RR + 3]);
    const float4 mx4 = block_max4(sharp4, red4, bc4);
    float4 e4;
    e4.x = expf(sharp4.x - mx4.x); e4.y = expf(sharp4.y - mx4.y);
    e4.z = expf(sharp4.z - mx4.z); e4.w = expf(sharp4.w - mx4.w);
    const float4 s4 = block_sum4(e4, red4, bc4);
    rcG[((size_t)b * RR + 0) * NN + n] = e4.x / s4.x;
    rcG[((size_t)b * RR + 1) * NN + n] = e4.y / s4.y;
    rcG[((size_t)b * RR + 2) * NN + n] = e4.z / s4.z;
    rcG[((size_t)b * RR + 3) * NN + n] = e4.w / s4.w;

    // ---- scalar sums S_rp, S_uww ----
    const float prec_n = pprec[b * NN + n];
    float4 sp4, sw4;
    sp4.x = ur[0] * prec_n; sp4.y = ur[1] * prec_n; sp4.z = ur[2] * prec_n; sp4.w = ur[3] * prec_n;
    const float4 SrpV = block_sum4(sp4, red4, bc4);
    sw4.x = ur[0] * ww; sw4.y = ur[1] * ww; sw4.z = ur[2] * ww; sw4.w = ur[3] * ww;
    const float4 SuwwV = block_sum4(sw4, red4, bc4);
    if (tid == 0) {
        SrpG[b * RR + 0] = SrpV.x; SrpG[b * RR + 1] = SrpV.y;
        SrpG[b * RR + 2] = SrpV.z; SrpG[b * RR + 3] = SrpV.w;
        SuwwG[b * RR + 0] = SuwwV.x; SuwwG[b * RR + 1] = SuwwV.y;
        SuwwG[b * RR + 2] = SuwwV.z; SuwwG[b * RR + 3] = SuwwV.w;
    }
}

// ---------------- K2a: row sums, one float4-streamed pass over L ----------------
// grid (64, 64), 512 thr = 8 waves; wave owns 2 rows.
// rowU[v][n] = sum_m L[n,m]*u_v[m]; rowV[v][n] = sum_m L[n,m]*ww[m]*u_v[m].
// acc[2][8] = 16 VGPRs; u/ww staged in LDS (off the vmem counter).
__global__ __launch_bounds__(512, 4) void row_kernel(
    const float* __restrict__ L, const float* __restrict__ prw,
    const float* __restrict__ wwG,
    float* __restrict__ rowP,     // [b][8][1024]
    float* __restrict__ diagG)    // [b][1024]
{
    __shared__ float uS[4][NN];
    __shared__ float wS[NN];

    const int s = blockIdx.x, b = blockIdx.y;
    const int t = threadIdx.x, lane = t & 63, wid = t >> 6;

    for (int k = t; k < NN; k += 512) {
        wS[k] = wwG[(b << 10) + k];
#pragma unroll
        for (int r = 0; r < 4; ++r)
            uS[r][k] = prw[((size_t)(b * 4 + r) << 10) + k];
    }
    __syncthreads();

    const int n0 = (s << 4) + (wid << 1);        // wave's rows: n0, n0+1
    const float* Lb = L + ((size_t)b << 20);
    const float* row0 = Lb + ((size_t)n0 << 10);
    const float* row1 = row0 + NN;

    float acc[2][8];
#pragma unroll
    for (int i = 0; i < 2; ++i)
#pragma unroll
        for (int v = 0; v < 8; ++v) acc[i][v] = 0.f;

#pragma unroll
    for (int c = 0; c < 4; ++c) {
        const int col = (c << 8) + (lane << 2);
        const float4 l0 = *(const float4*)&row0[col];
        const float4 l1 = *(const float4*)&row1[col];
        const float4 wv = *(const float4*)&wS[col];
        float4 w0, w1;
        w0.x = l0.x * wv.x; w0.y = l0.y * wv.y; w0.z = l0.z * wv.z; w0.w = l0.w * wv.w;
        w1.x = l1.x * wv.x; w1.y = l1.y * wv.y; w1.z = l1.z * wv.z; w1.w = l1.w * wv.w;
#pragma unroll
        for (int r = 0; r < 4; ++r) {
            const float4 uv = *(const float4*)&uS[r][col];
            acc[0][r]     = fmaf(l0.x, uv.x, fmaf(l0.y, uv.y, fmaf(l0.z, uv.z, fmaf(l0.w, uv.w, acc[0][r]))));
            acc[0][4 + r] = fmaf(w0.x, uv.x, fmaf(w0.y, uv.y, fmaf(w0.z, uv.z, fmaf(w0.w, uv.w, acc[0][4 + r]))));
            acc[1][r]     = fmaf(l1.x, uv.x, fmaf(l1.y, uv.y, fmaf(l1.z, uv.z, fmaf(l1.w, uv.w, acc[1][r]))));
            acc[1][4 + r] = fmaf(w1.x, uv.x, fmaf(w1.y, uv.y, fmaf(w1.z, uv.z, fmaf(w1.w, uv.w, acc[1][4 + r]))));
        }
    }

    // diagonal extraction (rows' lines are L1-hot)
    if (lane < 2) {
        const int n = n0 + lane;
        diagG[(b << 10) + n] = Lb[((size_t)n << 10) + n];
    }

    // butterfly-reduce the 16 values; lane q stores value q
#pragma unroll
    for (int i = 0; i < 2; ++i)
#pragma unroll
        for (int v = 0; v < 8; ++v) {
            float x = acc[i][v];
            x += __shfl_xor(x, 1, 64);  x += __shfl_xor(x, 2, 64);
            x += __shfl_xor(x, 4, 64);  x += __shfl_xor(x, 8, 64);
            x += __shfl_xor(x, 16, 64); x += __shfl_xor(x, 32, 64);
            if (lane == i * 8 + v)
                rowP[(((size_t)b * 8 + v) << 10) + n0 + i] = x;
        }
}

// ---------------- K2b: col sums, second float4-streamed pass over L ----------------
// grid (8, 64), 256 thr; thread owns 4 cols (float4). Stripe = 128 rows.
// colU[v][m] = sum_n L[n,m]*s_v[n], s = {u_r, u_r*ww}. cacc = 8 float4 = 32 VGPRs.
__global__ __launch_bounds__(256, 4) void col_kernel(
    const float* __restrict__ L, const float* __restrict__ prw,
    const float* __restrict__ wwG,
    float* __restrict__ colU)     // [b][8][1024], atomic-accumulated
{
    __shared__ float sL[128][8];   // per-row scalar table (broadcast reads)

    const int s = blockIdx.x, b = blockIdx.y;
    const int t = threadIdx.x;
    const int n0 = s << 7;

    if (t < 128) {
        const int n = n0 + t;
        const float ww = wwG[(b << 10) + n];
#pragma unroll
        for (int r = 0; r < 4; ++r) {
            const float u = prw[((size_t)(b * 4 + r) << 10) + n];
            sL[t][r]     = u;
            sL[t][4 + r] = u * ww;
        }
    }
    __syncthreads();

    const float* Lb = L + ((size_t)b << 20) + ((size_t)n0 << 10);
    const int col = t << 2;

    float4 cacc[8];
#pragma unroll
    for (int v = 0; v < 8; ++v) { cacc[v].x = 0.f; cacc[v].y = 0.f; cacc[v].z = 0.f; cacc[v].w = 0.f; }

#pragma unroll 4
    for (int i = 0; i < 128; ++i) {
        const float4 lv = *(const float4*)&Lb[((size_t)i << 10) + col];
        const float4 s0 = *(const float4*)&sL[i][0];
        const float4 s1 = *(const float4*)&sL[i][4];
        cacc[0].x = fmaf(lv.x, s0.x, cacc[0].x); cacc[0].y = fmaf(lv.y, s0.x, cacc[0].y);
        cacc[0].z = fmaf(lv.z, s0.x, cacc[0].z); cacc[0].w = fmaf(lv.w, s0.x, cacc[0].w);
        cacc[1].x = fmaf(lv.x, s0.y, cacc[1].x); cacc[1].y = fmaf(lv.y, s0.y, cacc[1].y);
        cacc[1].z = fmaf(lv.z, s0.y, cacc[1].z); cacc[1].w = fmaf(lv.w, s0.y, cacc[1].w);
        cacc[2].x = fmaf(lv.x, s0.z, cacc[2].x); cacc[2].y = fmaf(lv.y, s0.z, cacc[2].y);
        cacc[2].z = fmaf(lv.z, s0.z, cacc[2].z); cacc[2].w = fmaf(lv.w, s0.z, cacc[2].w);
        cacc[3].x = fmaf(lv.x, s0.w, cacc[3].x); cacc[3].y = fmaf(lv.y, s0.w, cacc[3].y);
        cacc[3].z = fmaf(lv.z, s0.w, cacc[3].z); cacc[3].w = fmaf(lv.w, s0.w, cacc[3].w);
        cacc[4].x = fmaf(lv.x, s1.x, cacc[4].x); cacc[4].y = fmaf(lv.y, s1.x, cacc[4].y);
        cacc[4].z = fmaf(lv.z, s1.x, cacc[4].z); cacc[4].w = fmaf(lv.w, s1.x, cacc[4].w);
        cacc[5].x = fmaf(lv.x, s1.y, cacc[5].x); cacc[5].y = fmaf(lv.y, s1.y, cacc[5].y);
        cacc[5].z = fmaf(lv.z, s1.y, cacc[5].z); cacc[5].w = fmaf(lv.w, s1.y, cacc[5].w);
        cacc[6].x = fmaf(lv.x, s1.z, cacc[6].x); cacc[6].y = fmaf(lv.y, s1.z, cacc[6].y);
        cacc[6].z = fmaf(lv.z, s1.z, cacc[6].z); cacc[6].w = fmaf(lv.w, s1.z, cacc[6].w);
        cacc[7].x = fmaf(lv.x, s1.w, cacc[7].x); cacc[7].y = fmaf(lv.y, s1.w, cacc[7].y);
        cacc[7].z = fmaf(lv.z, s1.w, cacc[7].z); cacc[7].w = fmaf(lv.w, s1.w, cacc[7].w);
    }

    const size_t base = ((size_t)b << 13) + col;
#pragma unroll
    for (int v = 0; v < 8; ++v) {
        unsafeAtomicAdd((float*)colU + base + (v << 10) + 0, cacc[v].x);
        unsafeAtomicAdd((float*)colU + base + (v << 10) + 1, cacc[v].y);
        unsafeAtomicAdd((float*)colU + base + (v << 10) + 2, cacc[v].z);
        unsafeAtomicAdd((float*)colU + base + (v << 10) + 3, cacc[v].w);
    }
}

// ---------------- K3: assemble read weights + read_words ----------------
__global__ __launch_bounds__(256) void combine_kernel(
    const float* __restrict__ memory, const float* __restrict__ prw,
    const float* __restrict__ pprec, const float* __restrict__ diagG,
    const float* __restrict__ evec_g, const float* __restrict__ wvec_g,
    const float* __restrict__ rmode_g,
    const float* __restrict__ wwG, const float* __restrict__ rcG,
    const float* __restrict__ rowP, const float* __restrict__ colU,
    const float* __restrict__ SrpG, const float* __restrict__ SuwwG,
    float* __restrict__ out)
{
    __shared__ float rwL[RR][256];
    __shared__ float wwS[256];

    const int b = blockIdx.y;
    const int n0 = blockIdx.x * 256;
    const int t = threadIdx.x;
    const int n = n0 + t;

    const float wwn = wwG[b * NN + n];
    wwS[t] = wwn;
    const float prec_n = pprec[b * NN + n];
    const float diag = diagG[(b << 10) + n];

#pragma unroll
    for (int r = 0; r < RR; ++r) {
        const size_t idx = ((size_t)b * RR + r) * NN + n;
        const float un = prw[idx];
        const float rc = rcG[idx];
        const float ru = rowP[(((size_t)b * 8 + r) << 10) + n];
        const float rv = rowP[(((size_t)b * 8 + 4 + r) << 10) + n];
        const float cuv = colU[((size_t)b << 13) + (r << 10) + n];
        const float cvv = colU[((size_t)b << 13) + ((4 + r) << 10) + n];
        const float Srp = SrpG[b * RR + r], Suww = SuwwG[b * RR + r];
        const float corr = un * (1.f - 2.f * wwn) * diag;
        const float fwd = (1.f - wwn) * ru - rv - corr + wwn * (Srp - un * prec_n);
        const float bwd = (1.f - wwn) * cuv - cvv - corr + prec_n * (Suww - un * wwn);
        const float m0 = rmode_g[((size_t)b * RR + r) * 3 + 0];
        const float m1 = rmode_g[((size_t)b * RR + r) * 3 + 1];
        const float m2 = rmode_g[((size_t)b * RR + r) * 3 + 2];
        const float mx = fmaxf(m0, fmaxf(m1, m2));
        const float e0 = expf(m0 - mx), e1 = expf(m1 - mx), e2 = expf(m2 - mx);
        const float inv = 1.f / (e0 + e1 + e2);
        rwL[r][t] = (e2 * inv) * rc + (e1 * inv) * fwd + (e0 * inv) * bwd;
    }
    __syncthreads();

    // partial read_words over this n-chunk
    const int r = t >> 6, w = t & 63;
    const float ev = evec_g[b * WD + w], wv = wvec_g[b * WD + w];
    float acc = 0.f;
    const float* mb = memory + ((size_t)b * NN + n0) * WD;
#pragma unroll 8
    for (int i = 0; i < 256; ++i) {
        const float m = mb[(size_t)i * WD + w];
        const float wwi = wwS[i];
        const float mn_ = m * (1.f - wwi * ev) + wwi * wv;
        acc = fmaf(rwL[r][i], mn_, acc);
    }
    unsafeAtomicAdd(&out[((size_t)b * RR + r) * WD + w], acc);
}

// ---------------- launch ----------------
extern "C" void kernel_launch(void* const* d_in, const int* in_sizes, int n_in,
                              void* d_out, int out_size, void* d_ws, size_t ws_size,
                              hipStream_t stream) {
    const float* memory = (const float*)d_in[0];
    const float* prw    = (const float*)d_in[1];
    const float* pww    = (const float*)d_in[2];
    const float* pusage = (const float*)d_in[3];
    const float* plink  = (const float*)d_in[4];
    const float* pprec  = (const float*)d_in[5];
    const float* rkeys  = (const float*)d_in[6];
    const float* rstr   = (const float*)d_in[7];
    const float* wkeys  = (const float*)d_in[8];
    const float* wstr   = (const float*)d_in[9];
    const float* wvec   = (const float*)d_in[10];
    const float* evec   = (const float*)d_in[11];
    const float* fg     = (const float*)d_in[12];
    const float* ag     = (const float*)d_in[13];
    const float* wg     = (const float*)d_in[14];
    const float* rmode  = (const float*)d_in[15];

    float* ws = (float*)d_ws;
    const size_t BN   = (size_t)BB * NN;        // 65536
    const size_t BRN  = (size_t)BB * RR * NN;   // 262144
    const size_t B8N  = (size_t)BB * 8 * NN;    // 524288

    float* wwG   = ws;
    float* rcG   = wwG + BN;
    float* rowP  = rcG + BRN;
    float* colU  = rowP + B8N;
    float* diagG = colU + B8N;
    float* Srp   = diagG + BN;
    float* Suww  = Srp + (size_t)BB * RR;

    hipMemsetAsync(d_out, 0, (size_t)out_size * sizeof(float), stream);

    prep_kernel<<<BB, 1024, 0, stream>>>(memory, prw, pww, pusage, pprec,
                                         rkeys, rstr, wkeys, wstr, wvec, evec,
                                         fg, ag, wg, wwG, rcG, Srp, Suww, colU);
    row_kernel<<<dim3(64, BB), 512, 0, stream>>>(plink, prw, wwG, rowP, diagG);
    col_kernel<<<dim3(8, BB), 256, 0, stream>>>(plink, prw, wwG, colU);
    combine_kernel<<<dim3(4, BB), 256, 0, stream>>>(memory, prw, pprec, diagG,
                                                    evec, wvec, rmode,
                                                    wwG, rcG, rowP, colU,
                                                    Srp, Suww, (float*)d_out);
}

// Round 5
// 606.885 us; speedup vs baseline: 1.8951x; 1.0422x over previous
//
#include <hip/hip_runtime.h>
#include <cmath>

#define NN 1024
#define BB 64
#define WD 64
#define RR 4
#define STRIPES 16   // fused link kernel: 16 row-stripes of 64 rows

constexpr float EPSF = 1e-6f;

// ---------------- device helpers ----------------
__device__ __forceinline__ float softplusf(float x) {
    return fmaxf(x, 0.f) + log1pf(expf(-fabsf(x)));
}

// block = 1024 threads (16 waves)
__device__ __forceinline__ float block_sum(float v, float* red, float* bc) {
#pragma unroll
    for (int o = 1; o < 64; o <<= 1) v += __shfl_xor(v, o, 64);
    const int wid = threadIdx.x >> 6, lane = threadIdx.x & 63;
    if (lane == 0) red[wid] = v;
    __syncthreads();
    if (wid == 0) {
        float x = (lane < 16) ? red[lane] : 0.f;
#pragma unroll
        for (int o = 1; o < 16; o <<= 1) x += __shfl_xor(x, o, 64);
        if (lane == 0) bc[0] = x;
    }
    __syncthreads();
    return bc[0];
}

__device__ __forceinline__ float block_max(float v, float* red, float* bc) {
#pragma unroll
    for (int o = 1; o < 64; o <<= 1) v = fmaxf(v, __shfl_xor(v, o, 64));
    const int wid = threadIdx.x >> 6, lane = threadIdx.x & 63;
    if (lane == 0) red[wid] = v;
    __syncthreads();
    if (wid == 0) {
        float x = (lane < 16) ? red[lane] : -INFINITY;
#pragma unroll
        for (int o = 1; o < 16; o <<= 1) x = fmaxf(x, __shfl_xor(x, o, 64));
        if (lane == 0) bc[0] = x;
    }
    __syncthreads();
    return bc[0];
}

__device__ __forceinline__ float4 block_sum4(float4 v, float4* red, float4* bc) {
#pragma unroll
    for (int o = 1; o < 64; o <<= 1) {
        v.x += __shfl_xor(v.x, o, 64); v.y += __shfl_xor(v.y, o, 64);
        v.z += __shfl_xor(v.z, o, 64); v.w += __shfl_xor(v.w, o, 64);
    }
    const int wid = threadIdx.x >> 6, lane = threadIdx.x & 63;
    if (lane == 0) red[wid] = v;
    __syncthreads();
    if (wid == 0) {
        float4 x;
        if (lane < 16) x = red[lane];
        else { x.x = 0.f; x.y = 0.f; x.z = 0.f; x.w = 0.f; }
#pragma unroll
        for (int o = 1; o < 16; o <<= 1) {
            x.x += __shfl_xor(x.x, o, 64); x.y += __shfl_xor(x.y, o, 64);
            x.z += __shfl_xor(x.z, o, 64); x.w += __shfl_xor(x.w, o, 64);
        }
        if (lane == 0) bc[0] = x;
    }
    __syncthreads();
    return bc[0];
}

__device__ __forceinline__ float4 block_max4(float4 v, float4* red, float4* bc) {
#pragma unroll
    for (int o = 1; o < 64; o <<= 1) {
        v.x = fmaxf(v.x, __shfl_xor(v.x, o, 64)); v.y = fmaxf(v.y, __shfl_xor(v.y, o, 64));
        v.z = fmaxf(v.z, __shfl_xor(v.z, o, 64)); v.w = fmaxf(v.w, __shfl_xor(v.w, o, 64));
    }
    const int wid = threadIdx.x >> 6, lane = threadIdx.x & 63;
    if (lane == 0) red[wid] = v;
    __syncthreads();
    if (wid == 0) {
        float4 x;
        if (lane < 16) x = red[lane];
        else { x.x = -INFINITY; x.y = -INFINITY; x.z = -INFINITY; x.w = -INFINITY; }
#pragma unroll
        for (int o = 1; o < 16; o <<= 1) {
            x.x = fmaxf(x.x, __shfl_xor(x.x, o, 64)); x.y = fmaxf(x.y, __shfl_xor(x.y, o, 64));
            x.z = fmaxf(x.z, __shfl_xor(x.z, o, 64)); x.w = fmaxf(x.w, __shfl_xor(x.w, o, 64));
        }
        if (lane == 0) bc[0] = x;
    }
    __syncthreads();
    return bc[0];
}

// ---------------- K1: per-batch prep ----------------
__global__ __launch_bounds__(1024) void prep_kernel(
    const float* __restrict__ memory, const float* __restrict__ prw,
    const float* __restrict__ pww, const float* __restrict__ pusage,
    const float* __restrict__ pprec,
    const float* __restrict__ rkeys_g, const float* __restrict__ rstr_g,
    const float* __restrict__ wkeys_g, const float* __restrict__ wstr_g,
    const float* __restrict__ wvec_g, const float* __restrict__ evec_g,
    const float* __restrict__ fg_g, const float* __restrict__ ag_g,
    const float* __restrict__ wg_g,
    float* __restrict__ wwG, float* __restrict__ rcG,
    float* __restrict__ SrpG, float* __restrict__ SuwwG)
{
    __shared__ float wkey[WD], wvecS[WD], evecS[WD], rkey[RR * WD];
    __shared__ float skey[NN];
    __shared__ int   sidx[NN];
    __shared__ float pArr[NN], wcArr[NN], allocArr[NN];
    __shared__ float red1[16], bc1[1];
    __shared__ float4 red4[16], bc4[1];

    const int b = blockIdx.x, tid = threadIdx.x, n = tid;

    if (tid < WD) {
        wkey[tid]  = wkeys_g[b * WD + tid];
        wvecS[tid] = wvec_g[b * WD + tid];
        evecS[tid] = evec_g[b * WD + tid];
    } else if (tid >= 128 && tid < 128 + RR * WD) {
        int k = tid - 128;
        rkey[k] = rkeys_g[b * RR * WD + k];
    }
    __syncthreads();

    // ---- usage after free gates ----
    float ur[RR];
#pragma unroll
    for (int r = 0; r < RR; ++r) ur[r] = prw[((size_t)b * RR + r) * NN + n];
    const float pw = pww[b * NN + n];
    const float pu = pusage[b * NN + n];
    float usage = pu + (1.f - pu) * pw;
    float phi = 1.f;
#pragma unroll
    for (int r = 0; r < RR; ++r) phi *= (1.f - fg_g[b * RR + r] * ur[r]);
    usage *= phi;

    // ---- write content weights (cosine + softmax) ----
    const float* mrow = memory + ((size_t)b * NN + n) * WD;
    float dot = 0.f, nrm = 0.f, knrm = 0.f;
#pragma unroll 4
    for (int w4 = 0; w4 < WD / 4; ++w4) {
        const float4 m = *(const float4*)(mrow + w4 * 4);
        const float4 k = *(const float4*)(wkey + w4 * 4);
        dot  += m.x * k.x + m.y * k.y + m.z * k.z + m.w * k.w;
        nrm  += m.x * m.x + m.y * m.y + m.z * m.z + m.w * m.w;
        knrm += k.x * k.x + k.y * k.y + k.z * k.z + k.w * k.w;
    }
    const float sim = dot / (sqrtf(knrm + EPSF) * sqrtf(nrm + EPSF) + EPSF);
    const float sharp = sim * softplusf(wstr_g[b]);
    const float mxw = block_max(sharp, red1, bc1);
    const float exw = expf(sharp - mxw);
    const float smw = block_sum(exw, red1, bc1);
    wcArr[n] = exw / smw;

    // ---- allocation: stable descending sort of nonusage ----
    const float ue = EPSF + (1.f - EPSF) * usage;
    skey[n] = 1.f - ue;
    sidx[n] = n;
    __syncthreads();
    for (int k = 2; k <= NN; k <<= 1) {
        for (int j = k >> 1; j > 0; j >>= 1) {
            const int ixj = tid ^ j;
            if (ixj > tid) {
                const float ka = skey[tid], kb = skey[ixj];
                const int ia = sidx[tid], ib = sidx[ixj];
                const bool precBA = (kb > ka) || (kb == ka && ib < ia);
                const bool precAB = (ka > kb) || (ka == kb && ia < ib);
                const bool dosw = ((tid & k) == 0) ? precBA : precAB;
                if (dosw) { skey[tid] = kb; skey[ixj] = ka; sidx[tid] = ib; sidx[ixj] = ia; }
            }
            __syncthreads();
        }
    }
    // exclusive product scan of sorted usage
    pArr[n] = (n == 0) ? 1.f : (1.f - skey[n - 1]);
    __syncthreads();
    for (int off = 1; off < NN; off <<= 1) {
        const float t = (n >= off) ? pArr[n - off] : 1.f;
        __syncthreads();
        pArr[n] *= t;
        __syncthreads();
    }
    allocArr[sidx[n]] = skey[n] * pArr[n];
    __syncthreads();

    const float agv = ag_g[b], wgv = wg_g[b];
    const float ww = wgv * (agv * allocArr[n] + (1.f - agv) * wcArr[n]);
    wwG[b * NN + n] = ww;

    // ---- read content weights vs memory_new (recomputed inline) ----
    float rdot0 = 0, rdot1 = 0, rdot2 = 0, rdot3 = 0, nn2 = 0;
    float rk0 = 0, rk1 = 0, rk2 = 0, rk3 = 0;
#pragma unroll 4
    for (int w4 = 0; w4 < WD / 4; ++w4) {
        const float4 m = *(const float4*)(mrow + w4 * 4);
        const float4 e = *(const float4*)(evecS + w4 * 4);
        const float4 v = *(const float4*)(wvecS + w4 * 4);
        float4 mn_;
        mn_.x = m.x * (1.f - ww * e.x) + ww * v.x;
        mn_.y = m.y * (1.f - ww * e.y) + ww * v.y;
        mn_.z = m.z * (1.f - ww * e.z) + ww * v.z;
        mn_.w = m.w * (1.f - ww * e.w) + ww * v.w;
        nn2 += mn_.x * mn_.x + mn_.y * mn_.y + mn_.z * mn_.z + mn_.w * mn_.w;
        const float4 k0 = *(const float4*)(rkey + 0 * WD + w4 * 4);
        const float4 k1 = *(const float4*)(rkey + 1 * WD + w4 * 4);
        const float4 k2 = *(const float4*)(rkey + 2 * WD + w4 * 4);
        const float4 k3 = *(const float4*)(rkey + 3 * WD + w4 * 4);
        rdot0 += k0.x * mn_.x + k0.y * mn_.y + k0.z * mn_.z + k0.w * mn_.w;
        rdot1 += k1.x * mn_.x + k1.y * mn_.y + k1.z * mn_.z + k1.w * mn_.w;
        rdot2 += k2.x * mn_.x + k2.y * mn_.y + k2.z * mn_.z + k2.w * mn_.w;
        rdot3 += k3.x * mn_.x + k3.y * mn_.y + k3.z * mn_.z + k3.w * mn_.w;
        rk0 += k0.x * k0.x + k0.y * k0.y + k0.z * k0.z + k0.w * k0.w;
        rk1 += k1.x * k1.x + k1.y * k1.y + k1.z * k1.z + k1.w * k1.w;
        rk2 += k2.x * k2.x + k2.y * k2.y + k2.z * k2.z + k2.w * k2.w;
        rk3 += k3.x * k3.x + k3.y * k3.y + k3.z * k3.z + k3.w * k3.w;
    }
    const float mnn = sqrtf(nn2 + EPSF);
    float4 sharp4;
    sharp4.x = rdot0 / (sqrtf(rk0 + EPSF) * mnn + EPSF) * softplusf(rstr_g[b * RR + 0]);
    sharp4.y = rdot1 / (sqrtf(rk1 + EPSF) * mnn + EPSF) * softplusf(rstr_g[b * RR + 1]);
    sharp4.z = rdot2 / (sqrtf(rk2 + EPSF) * mnn + EPSF) * softplusf(rstr_g[b * RR + 2]);
    sharp4.w = rdot3 / (sqrtf(rk3 + EPSF) * mnn + EPSF) * softplusf(rstr_g[b * RR + 3]);
    const float4 mx4 = block_max4(sharp4, red4, bc4);
    float4 e4;
    e4.x = expf(sharp4.x - mx4.x); e4.y = expf(sharp4.y - mx4.y);
    e4.z = expf(sharp4.z - mx4.z); e4.w = expf(sharp4.w - mx4.w);
    const float4 s4 = block_sum4(e4, red4, bc4);
    rcG[((size_t)b * RR + 0) * NN + n] = e4.x / s4.x;
    rcG[((size_t)b * RR + 1) * NN + n] = e4.y / s4.y;
    rcG[((size_t)b * RR + 2) * NN + n] = e4.z / s4.z;
    rcG[((size_t)b * RR + 3) * NN + n] = e4.w / s4.w;

    // ---- scalar sums S_rp, S_uww ----
    const float prec_n = pprec[b * NN + n];
    float4 sp4, sw4;
    sp4.x = ur[0] * prec_n; sp4.y = ur[1] * prec_n; sp4.z = ur[2] * prec_n; sp4.w = ur[3] * prec_n;
    const float4 SrpV = block_sum4(sp4, red4, bc4);
    sw4.x = ur[0] * ww; sw4.y = ur[1] * ww; sw4.z = ur[2] * ww; sw4.w = ur[3] * ww;
    const float4 SuwwV = block_sum4(sw4, red4, bc4);
    if (tid == 0) {
        SrpG[b * RR + 0] = SrpV.x; SrpG[b * RR + 1] = SrpV.y;
        SrpG[b * RR + 2] = SrpV.z; SrpG[b * RR + 3] = SrpV.w;
        SuwwG[b * RR + 0] = SuwwV.x; SuwwG[b * RR + 1] = SuwwV.y;
        SuwwG[b * RR + 2] = SuwwV.z; SuwwG[b * RR + 3] = SuwwV.w;
    }
}

// ---------------- K2: fused single pass over prev_link (256 MB) ----------------
// grid (16, 64), 256 thr = 4 waves. Block owns 64 rows x all 1024 cols;
// thread owns 4 fixed cols (float4 loads).
// Col sums: cacc[8] float4 resident whole kernel -> block-exclusive
//           non-atomic store to colPart[stripe][b][8][1024].
// Row sums: thread-resident u/uw consts (8 x float4), per-row shfl butterfly
//           -> rowAcc LDS -> block-end 4-way sum -> non-atomic rowP store.
__global__ __launch_bounds__(256, 4) void link_fused_kernel(
    const float* __restrict__ L, const float* __restrict__ prw,
    const float* __restrict__ wwG,
    float* __restrict__ rowP,      // [b][8][1024]
    float* __restrict__ colPart,   // [16][b][8][1024]
    float* __restrict__ diagG)     // [b][1024]
{
    __shared__ float sRow[64][8];        // per-row broadcast scalars (u, u*ww)
    __shared__ float rowAcc[64][4][8];   // per-row per-wave partials (8 KB)

    const int s = blockIdx.x, b = blockIdx.y;
    const int t = threadIdx.x, lane = t & 63, wid = t >> 6;
    const int i0 = s << 6;
    const int col = t << 2;

    const float* ub = prw + ((size_t)(b * RR) << 10);
    const float* wb = wwG + ((size_t)b << 10);
    const float* Lb = L + ((size_t)b << 20) + ((size_t)i0 << 10);

    // stage per-row scalars + diag
    if (t < 64) {
        const int n = i0 + t;
        const float ww = wb[n];
#pragma unroll
        for (int r = 0; r < RR; ++r) {
            const float u = ub[(r << 10) + n];
            sRow[t][r]     = u;
            sRow[t][4 + r] = u * ww;
        }
        diagG[(b << 10) + n] = L[((size_t)b << 20) + ((size_t)n << 10) + n];
    }

    // thread-resident u constants for its 4 cols
    float4 ucu[4], ucw[4];
    {
        const float4 wwc = *(const float4*)&wb[col];
#pragma unroll
        for (int r = 0; r < RR; ++r) {
            const float4 u = *(const float4*)&ub[(r << 10) + col];
            ucu[r] = u;
            ucw[r].x = u.x * wwc.x; ucw[r].y = u.y * wwc.y;
            ucw[r].z = u.z * wwc.z; ucw[r].w = u.w * wwc.w;
        }
    }

    float4 cacc[8];
#pragma unroll
    for (int v = 0; v < 8; ++v) { cacc[v].x = 0.f; cacc[v].y = 0.f; cacc[v].z = 0.f; cacc[v].w = 0.f; }

    __syncthreads();

#pragma unroll 2
    for (int i = 0; i < 64; ++i) {
        const float4 lv = *(const float4*)&Lb[((size_t)i << 10) + col];

        // col accumulation (broadcast scalars from LDS)
        const float4 s0 = *(const float4*)&sRow[i][0];
        const float4 s1 = *(const float4*)&sRow[i][4];
        cacc[0].x = fmaf(lv.x, s0.x, cacc[0].x); cacc[0].y = fmaf(lv.y, s0.x, cacc[0].y);
        cacc[0].z = fmaf(lv.z, s0.x, cacc[0].z); cacc[0].w = fmaf(lv.w, s0.x, cacc[0].w);
        cacc[1].x = fmaf(lv.x, s0.y, cacc[1].x); cacc[1].y = fmaf(lv.y, s0.y, cacc[1].y);
        cacc[1].z = fmaf(lv.z, s0.y, cacc[1].z); cacc[1].w = fmaf(lv.w, s0.y, cacc[1].w);
        cacc[2].x = fmaf(lv.x, s0.z, cacc[2].x); cacc[2].y = fmaf(lv.y, s0.z, cacc[2].y);
        cacc[2].z = fmaf(lv.z, s0.z, cacc[2].z); cacc[2].w = fmaf(lv.w, s0.z, cacc[2].w);
        cacc[3].x = fmaf(lv.x, s0.w, cacc[3].x); cacc[3].y = fmaf(lv.y, s0.w, cacc[3].y);
        cacc[3].z = fmaf(lv.z, s0.w, cacc[3].z); cacc[3].w = fmaf(lv.w, s0.w, cacc[3].w);
        cacc[4].x = fmaf(lv.x, s1.x, cacc[4].x); cacc[4].y = fmaf(lv.y, s1.x, cacc[4].y);
        cacc[4].z = fmaf(lv.z, s1.x, cacc[4].z); cacc[4].w = fmaf(lv.w, s1.x, cacc[4].w);
        cacc[5].x = fmaf(lv.x, s1.y, cacc[5].x); cacc[5].y = fmaf(lv.y, s1.y, cacc[5].y);
        cacc[5].z = fmaf(lv.z, s1.y, cacc[5].z); cacc[5].w = fmaf(lv.w, s1.y, cacc[5].w);
        cacc[6].x = fmaf(lv.x, s1.z, cacc[6].x); cacc[6].y = fmaf(lv.y, s1.z, cacc[6].y);
        cacc[6].z = fmaf(lv.z, s1.z, cacc[6].z); cacc[6].w = fmaf(lv.w, s1.z, cacc[6].w);
        cacc[7].x = fmaf(lv.x, s1.w, cacc[7].x); cacc[7].y = fmaf(lv.y, s1.w, cacc[7].y);
        cacc[7].z = fmaf(lv.z, s1.w, cacc[7].z); cacc[7].w = fmaf(lv.w, s1.w, cacc[7].w);

        // row partials: 8 dot4s against resident consts
        float p[8];
#pragma unroll
        for (int r = 0; r < RR; ++r) {
            p[r]     = fmaf(lv.x, ucu[r].x, fmaf(lv.y, ucu[r].y, fmaf(lv.z, ucu[r].z, lv.w * ucu[r].w)));
            p[4 + r] = fmaf(lv.x, ucw[r].x, fmaf(lv.y, ucw[r].y, fmaf(lv.z, ucw[r].z, lv.w * ucw[r].w)));
        }
        // butterfly-reduce each value over the wave; lane v keeps value v
        float out = 0.f;
#pragma unroll
        for (int v = 0; v < 8; ++v) {
            float x = p[v];
            x += __shfl_xor(x, 1, 64);  x += __shfl_xor(x, 2, 64);
            x += __shfl_xor(x, 4, 64);  x += __shfl_xor(x, 8, 64);
            x += __shfl_xor(x, 16, 64); x += __shfl_xor(x, 32, 64);
            if (lane == v) out = x;
        }
        if (lane < 8) rowAcc[i][wid][lane] = out;
    }

    // block-exclusive col-partial store (coalesced float4)
    {
        const size_t base = (((size_t)s * BB + b) * 8) << 10;
#pragma unroll
        for (int v = 0; v < 8; ++v)
            *(float4*)&colPart[base + ((size_t)v << 10) + col] = cacc[v];
    }

    __syncthreads();
    // block-end row reduce: 512 outputs, 256 threads -> 2 each
#pragma unroll
    for (int k = 0; k < 2; ++k) {
        const int idx = t + k * 256;         // idx = row*8 + v
        const int row = idx >> 3, v = idx & 7;
        const float sum = rowAcc[row][0][v] + rowAcc[row][1][v]
                        + rowAcc[row][2][v] + rowAcc[row][3][v];
        rowP[(((size_t)b * 8 + v) << 10) + i0 + row] = sum;
    }
}

// ---------------- K3: assemble read weights + read_words ----------------
__global__ __launch_bounds__(256) void combine_kernel(
    const float* __restrict__ memory, const float* __restrict__ prw,
    const float* __restrict__ pprec, const float* __restrict__ diagG,
    const float* __restrict__ evec_g, const float* __restrict__ wvec_g,
    const float* __restrict__ rmode_g,
    const float* __restrict__ wwG, const float* __restrict__ rcG,
    const float* __restrict__ rowP, const float* __restrict__ colPart,
    const float* __restrict__ SrpG, const float* __restrict__ SuwwG,
    float* __restrict__ out)
{
    __shared__ float rwL[RR][256];
    __shared__ float wwS[256];

    const int b = blockIdx.y;
    const int n0 = blockIdx.x * 256;
    const int t = threadIdx.x;
    const int n = n0 + t;

    const float wwn = wwG[b * NN + n];
    wwS[t] = wwn;
    const float prec_n = pprec[b * NN + n];
    const float diag = diagG[(b << 10) + n];

#pragma unroll
    for (int r = 0; r < RR; ++r) {
        const size_t idx = ((size_t)b * RR + r) * NN + n;
        const float un = prw[idx];
        const float rc = rcG[idx];
        const float ru = rowP[(((size_t)b * 8 + r) << 10) + n];
        const float rv = rowP[(((size_t)b * 8 + 4 + r) << 10) + n];
        float cuv = 0.f, cvv = 0.f;
#pragma unroll
        for (int s2 = 0; s2 < STRIPES; ++s2) {
            const size_t base = (((size_t)s2 * BB + b) * 8) << 10;
            cuv += colPart[base + ((size_t)r << 10) + n];
            cvv += colPart[base + ((size_t)(4 + r) << 10) + n];
        }
        const float Srp = SrpG[b * RR + r], Suww = SuwwG[b * RR + r];
        const float corr = un * (1.f - 2.f * wwn) * diag;
        const float fwd = (1.f - wwn) * ru - rv - corr + wwn * (Srp - un * prec_n);
        const float bwd = (1.f - wwn) * cuv - cvv - corr + prec_n * (Suww - un * wwn);
        const float m0 = rmode_g[((size_t)b * RR + r) * 3 + 0];
        const float m1 = rmode_g[((size_t)b * RR + r) * 3 + 1];
        const float m2 = rmode_g[((size_t)b * RR + r) * 3 + 2];
        const float mx = fmaxf(m0, fmaxf(m1, m2));
        const float e0 = expf(m0 - mx), e1 = expf(m1 - mx), e2 = expf(m2 - mx);
        const float inv = 1.f / (e0 + e1 + e2);
        rwL[r][t] = (e2 * inv) * rc + (e1 * inv) * fwd + (e0 * inv) * bwd;
    }
    __syncthreads();

    // partial read_words over this n-chunk
    const int r = t >> 6, w = t & 63;
    const float ev = evec_g[b * WD + w], wv = wvec_g[b * WD + w];
    float acc = 0.f;
    const float* mb = memory + ((size_t)b * NN + n0) * WD;
#pragma unroll 8
    for (int i = 0; i < 256; ++i) {
        const float m = mb[(size_t)i * WD + w];
        const float wwi = wwS[i];
        const float mn_ = m * (1.f - wwi * ev) + wwi * wv;
        acc = fmaf(rwL[r][i], mn_, acc);
    }
    unsafeAtomicAdd(&out[((size_t)b * RR + r) * WD + w], acc);
}

// ---------------- launch ----------------
extern "C" void kernel_launch(void* const* d_in, const int* in_sizes, int n_in,
                              void* d_out, int out_size, void* d_ws, size_t ws_size,
                              hipStream_t stream) {
    const float* memory = (const float*)d_in[0];
    const float* prw    = (const float*)d_in[1];
    const float* pww    = (const float*)d_in[2];
    const float* pusage = (const float*)d_in[3];
    const float* plink  = (const float*)d_in[4];
    const float* pprec  = (const float*)d_in[5];
    const float* rkeys  = (const float*)d_in[6];
    const float* rstr   = (const float*)d_in[7];
    const float* wkeys  = (const float*)d_in[8];
    const float* wstr   = (const float*)d_in[9];
    const float* wvec   = (const float*)d_in[10];
    const float* evec   = (const float*)d_in[11];
    const float* fg     = (const float*)d_in[12];
    const float* ag     = (const float*)d_in[13];
    const float* wg     = (const float*)d_in[14];
    const float* rmode  = (const float*)d_in[15];

    float* ws = (float*)d_ws;
    const size_t BN   = (size_t)BB * NN;                 // 65536
    const size_t BRN  = (size_t)BB * RR * NN;            // 262144
    const size_t B8N  = (size_t)BB * 8 * NN;             // 524288
    const size_t COLP = (size_t)STRIPES * BB * 8 * NN;   // 8388608

    float* wwG   = ws;
    float* rcG   = wwG + BN;
    float* rowP  = rcG + BRN;
    float* colP  = rowP + B8N;
    float* diagG = colP + COLP;
    float* Srp   = diagG + BN;
    float* Suww  = Srp + (size_t)BB * RR;

    hipMemsetAsync(d_out, 0, (size_t)out_size * sizeof(float), stream);

    prep_kernel<<<BB, 1024, 0, stream>>>(memory, prw, pww, pusage, pprec,
                                         rkeys, rstr, wkeys, wstr, wvec, evec,
                                         fg, ag, wg, wwG, rcG, Srp, Suww);
    link_fused_kernel<<<dim3(STRIPES, BB), 256, 0, stream>>>(plink, prw, wwG,
                                                             rowP, colP, diagG);
    combine_kernel<<<dim3(4, BB), 256, 0, stream>>>(memory, prw, pprec, diagG,
                                                    evec, wvec, rmode,
                                                    wwG, rcG, rowP, colP,
                                                    Srp, Suww, (float*)d_out);
}